// Round 7
// baseline (124.706 us; speedup 1.0000x reference)
//
#include <hip/hip_runtime.h>
#include <hip/hip_bf16.h>

typedef __hip_bfloat16 bf16;
typedef unsigned short u16;
typedef unsigned int u32;

typedef __bf16 bf16x8 __attribute__((ext_vector_type(8)));
typedef float f32x4 __attribute__((ext_vector_type(4)));

__device__ __forceinline__ float bf2f(bf16 v) { return __bfloat162float(v); }
__device__ __forceinline__ float us2f(u16 u) {
    union { u32 i; float f; } c; c.i = ((u32)u) << 16; return c.f;
}
__device__ __forceinline__ u16 f2u(float f) {
    union { bf16 b; u16 u; } c; c.b = __float2bfloat16(f); return c.u;
}

// ---------------------------------------------------------------------------
// K1 (MFMA GEMM): km/qm/xm = conv1x1. Blocks 0..63 zero the covariance
// partials arena. (R6-proven, unchanged.)
// ---------------------------------------------------------------------------
__global__ __launch_bounds__(256) void k_proj(
    const float* __restrict__ x, const float* __restrict__ vessel,
    const float* __restrict__ wk, const float* __restrict__ bk,
    const float* __restrict__ wq, const float* __restrict__ bq,
    const float* __restrict__ wx, const float* __restrict__ bx,
    bf16* __restrict__ km, bf16* __restrict__ qm, bf16* __restrict__ xm,
    float* __restrict__ partials)
{
    __shared__ u16 xs[64 * 264];
    __shared__ u16 wsh[48 * 264];
    const int tid = threadIdx.x;
    const int bid = blockIdx.x;
    const int nh = bid & 1;
    const int pt = bid >> 1;
    const int b  = pt >> 6;
    const int p0 = (pt & 63) * 64;

    if (bid < 64) {
#pragma unroll
        for (int i = 0; i < 5; ++i) {
            const int idx = tid + i * 256;
            if (idx < 1056) partials[bid * 1056 + idx] = 0.f;
        }
    }

#pragma unroll
    for (int i = 0; i < 16; ++i) {
        const int idx4 = tid + i * 256;
        const int ch = idx4 >> 4;
        const int px4 = (idx4 & 15) * 4;
        const float4 v = *(const float4*)&x[(b * 256 + ch) * 4096 + p0 + px4];
        xs[(px4 + 0) * 264 + ch] = f2u(v.x);
        xs[(px4 + 1) * 264 + ch] = f2u(v.y);
        xs[(px4 + 2) * 264 + ch] = f2u(v.z);
        xs[(px4 + 3) * 264 + ch] = f2u(v.w);
    }
#pragma unroll
    for (int i = 0; i < 12; ++i) {
        const int idx4 = tid + i * 256;
        const int o = idx4 >> 6;
        const int ch4 = (idx4 & 63) * 4;
        const int go = nh * 48 + o;
        const float* wp = (go < 32) ? wk : ((go < 64) ? wq : wx);
        const float4 v = *(const float4*)&wp[(go & 31) * 256 + ch4];
        wsh[o * 264 + ch4 + 0] = f2u(v.x);
        wsh[o * 264 + ch4 + 1] = f2u(v.y);
        wsh[o * 264 + ch4 + 2] = f2u(v.z);
        wsh[o * 264 + ch4 + 3] = f2u(v.w);
    }
    __syncthreads();

    const int w = tid >> 6;
    const int lane = tid & 63;
    const int lm = lane & 15, quad = lane >> 4;

    f32x4 acc0 = {0.f, 0.f, 0.f, 0.f};
    f32x4 acc1 = {0.f, 0.f, 0.f, 0.f};
    f32x4 acc2 = {0.f, 0.f, 0.f, 0.f};
#pragma unroll
    for (int kk = 0; kk < 8; ++kk) {
        const int k0 = kk * 32 + quad * 8;
        const bf16x8 a  = *(const bf16x8*)&xs[(w * 16 + lm) * 264 + k0];
        const bf16x8 b0 = *(const bf16x8*)&wsh[(0 + lm) * 264 + k0];
        const bf16x8 b1 = *(const bf16x8*)&wsh[(16 + lm) * 264 + k0];
        const bf16x8 b2 = *(const bf16x8*)&wsh[(32 + lm) * 264 + k0];
        acc0 = __builtin_amdgcn_mfma_f32_16x16x32_bf16(a, b0, acc0, 0, 0, 0);
        acc1 = __builtin_amdgcn_mfma_f32_16x16x32_bf16(a, b1, acc1, 0, 0, 0);
        acc2 = __builtin_amdgcn_mfma_f32_16x16x32_bf16(a, b2, acc2, 0, 0, 0);
    }
#pragma unroll
    for (int t = 0; t < 3; ++t) {
        const f32x4 acc = (t == 0) ? acc0 : ((t == 1) ? acc1 : acc2);
        const int go = nh * 48 + t * 16 + lm;
        const float* bs = (go < 32) ? bk : ((go < 64) ? bq : bx);
        const float bias = bs[go & 31];
        bf16* dst = (go < 32) ? km : ((go < 64) ? qm : xm);
#pragma unroll
        for (int rg = 0; rg < 4; ++rg) {
            const int px = p0 + w * 16 + quad * 4 + rg;
            float vv = acc[rg] + bias;
            if (go < 32) vv *= vessel[b * 4096 + px];
            dst[(b * 4096 + px) * 32 + (go & 31)] = __float2bfloat16(vv);
        }
    }
}

// ---------------------------------------------------------------------------
// K2 (MFMA): 4-scale local attention, block = 4x8 px tile, grid 512.
// R7 re-architecture:
//  - Two LDS arenas: A1 (15360 B): kT -> xTt;  A2 (25088 B): S -> {P, preT}.
//    Total 40448 B -> 4 blocks/CU (was 3, 53248 B).
//  - X halo: global loads ISSUE at start (regs), LDS write deferred to after
//    Phase A into kT's dead arena (T14 async-stage; latency hides under QK^T).
//  - Phase B: thread owns 24 CONTIGUOUS positions -> S reads 6x float4,
//    P writes 3x uint4 (was 24+24 scalar). Barrier between pass1/pass2
//    (required anyway: P aliases S).
//  - Q fragments deduped: 2 global loads/lane (was 6).
// Cov partial: symmetric -> wave 2's tile (1,0) skipped, rebuilt in k_out.
// ---------------------------------------------------------------------------
__global__ __launch_bounds__(256, 4) void k_attn(
    const bf16* __restrict__ km, const bf16* __restrict__ qm,
    const bf16* __restrict__ xm, bf16* __restrict__ pre,
    float* __restrict__ partials)
{
    __shared__ u16 A1[192 * 40];     // 15360 B: kT [pos][ch]; xTt after A
    __shared__ float A2f[32 * 196];  // 25088 B: S [px][pos]; P+preT after B
    u16* kT  = A1;
    u16* xTt = A1;                   // [ch][pos] stride 200 -> 12800 B
    float* S = A2f;
    u16* P    = (u16*)A2f;           // [px*200+pos], 12800 B (aliases S)
    u16* preT = (u16*)A2f + 6400;    // byte 12800..15360 (aliases S tail)

    const int tid = threadIdx.x;
    const int b = blockIdx.x >> 7;
    const int t128 = blockIdx.x & 127;
    const int h0 = (t128 >> 3) * 4;          // 16 row-tiles of 4
    const int w0 = (t128 & 7) * 8;           // 8 col-tiles of 8
    const u16* uk = (const u16*)km;
    const u16* ux = (const u16*)xm;
    const u16* uq = (const u16*)qm;
    const uint4 z4 = {0u, 0u, 0u, 0u};

    const int w = tid >> 6;
    const int lane = tid & 63;
    const int lm = lane & 15, quad = lane >> 4;

    // stage kT [pos][ch]; ISSUE X loads into regs (written to LDS later)
    uint4 xv[3];
#pragma unroll
    for (int i = 0; i < 3; ++i) {
        const int idx4 = tid + i * 256;      // 0..767
        const int pos = idx4 >> 2, c8 = idx4 & 3;
        const int gh = h0 - 4 + (pos >> 4), gw = w0 - 4 + (pos & 15);
        uint4 kv = z4;
        xv[i] = z4;
        if (gh >= 0 && gh < 64 && gw >= 0 && gw < 64) {
            const int g = ((b << 12) + (gh << 6) + gw) * 32 + c8 * 8;
            kv = *(const uint4*)&uk[g];
            xv[i] = *(const uint4*)&ux[g];
        }
        *(uint4*)&kT[pos * 40 + c8 * 8] = kv;
    }
    // Q fragments: only 2 distinct per lane (m = 0,1)
    bf16x8 qa[2];
#pragma unroll
    for (int m = 0; m < 2; ++m) {
        const int am = m * 16 + lm;
        const int qgh = h0 + (am >> 3), qgw = w0 + (am & 7);
        qa[m] = *(const bf16x8*)&uq[(((b << 12) + (qgh << 6) + qgw) << 5) + quad * 8];
    }
    __syncthreads();

    // Phase A: S tiles. 24 tiles (m 0..1, n 0..11), wave w takes t=w+4i.
#pragma unroll
    for (int i = 0; i < 6; ++i) {
        const int t = w + i * 4;
        const int m = t / 12, n = t - m * 12;
        const bf16x8 bb = *(const bf16x8*)&kT[(n * 16 + lm) * 40 + quad * 8];
        f32x4 acc = {0.f, 0.f, 0.f, 0.f};
        acc = __builtin_amdgcn_mfma_f32_16x16x32_bf16(qa[m], bb, acc, 0, 0, 0);
#pragma unroll
        for (int rg = 0; rg < 4; ++rg)
            S[(m * 16 + quad * 4 + rg) * 196 + n * 16 + lm] = acc[rg];
    }
    __syncthreads();

    // Phase B pass 1: thread (px,cg) owns 24 contiguous positions
    const int px = tid >> 3, cg = tid & 7;
    const int ty = px >> 3, tx = px & 7;
    float e[24];
    float Z3 = 0.f, Z5 = 0.f, Z7 = 0.f, Z9 = 0.f;
#pragma unroll
    for (int i4 = 0; i4 < 6; ++i4) {
        const f32x4 sv = *(const f32x4*)&S[px * 196 + cg * 24 + i4 * 4];
#pragma unroll
        for (int k = 0; k < 4; ++k) {
            const int j = i4 * 4 + k;
            const int pos = cg * 24 + j;
            const int hy = pos >> 4, hx = pos & 15;
            const int dy = hy - 4 - ty, dx = hx - 4 - tx;
            const int ady = dy < 0 ? -dy : dy, adx = dx < 0 ? -dx : dx;
            const int r = ady > adx ? ady : adx;
            const float ev = (r <= 4) ? __expf(sv[k]) : 0.f;
            e[j] = ev;
            if (r <= 1) Z3 += ev;
            if (r <= 2) Z5 += ev;
            if (r <= 3) Z7 += ev;
            Z9 += ev;
        }
    }
    // xTt writes into kT's dead arena (X regs arrive; latency already hidden)
#pragma unroll
    for (int i = 0; i < 3; ++i) {
        const int idx4 = tid + i * 256;
        const int pos = idx4 >> 2, c8 = idx4 & 3;
        const u16* xu = (const u16*)&xv[i];
#pragma unroll
        for (int t = 0; t < 8; ++t)
            xTt[(c8 * 8 + t) * 200 + pos] = xu[t];
    }
#pragma unroll
    for (int m = 1; m <= 4; m <<= 1) {
        Z3 += __shfl_xor(Z3, m);
        Z5 += __shfl_xor(Z5, m);
        Z7 += __shfl_xor(Z7, m);
        Z9 += __shfl_xor(Z9, m);
    }
    __syncthreads();   // all S reads + xTt writes complete (P aliases S)

    // Phase B pass 2: P writes, 3x uint4 per thread
    const float iZ3 = 1.f / Z3, iZ5 = 1.f / Z5, iZ7 = 1.f / Z7, iZ9 = 1.f / Z9;
    __attribute__((aligned(16))) u16 pw[24];
#pragma unroll
    for (int j = 0; j < 24; ++j) {
        const int pos = cg * 24 + j;
        const int hy = pos >> 4, hx = pos & 15;
        const int dy = hy - 4 - ty, dx = hx - 4 - tx;
        const int ady = dy < 0 ? -dy : dy, adx = dx < 0 ? -dx : dx;
        const int r = ady > adx ? ady : adx;
        float coef = iZ9;
        if (r <= 1) coef += iZ3;
        if (r <= 2) coef += iZ5;
        if (r <= 3) coef += iZ7;
        pw[j] = f2u(e[j] * coef);
    }
#pragma unroll
    for (int v = 0; v < 3; ++v)
        *(uint4*)&P[px * 200 + cg * 24 + v * 8] = *(const uint4*)&pw[v * 8];
    __syncthreads();

    // Phase C: pre(32x32) = P(32x192) . X^T : wave w -> tile (m0,n0)
    const int m0 = w >> 1, n0 = w & 1;
    f32x4 acc = {0.f, 0.f, 0.f, 0.f};
#pragma unroll
    for (int kk = 0; kk < 6; ++kk) {
        const int k0 = kk * 32 + quad * 8;
        const bf16x8 a = *(const bf16x8*)&P[(m0 * 16 + lm) * 200 + k0];
        const bf16x8 bb = *(const bf16x8*)&xTt[(n0 * 16 + lm) * 200 + k0];
        acc = __builtin_amdgcn_mfma_f32_16x16x32_bf16(a, bb, acc, 0, 0, 0);
    }
#pragma unroll
    for (int rg = 0; rg < 4; ++rg) {
        const int pl = m0 * 16 + quad * 4 + rg;
        const int gh = h0 + (pl >> 3), gw = w0 + (pl & 7);
        pre[(((b << 12) + (gh << 6) + gw) << 5) + n0 * 16 + lm] =
            __float2bfloat16(acc[rg]);
        // transposed bf16 copy for the covariance MFMA: preT[ch][px]
        // (preT sits at S-arena byte 12800+, disjoint from P's 0..12800)
        preT[(n0 * 16 + lm) * 40 + pl] = f2u(acc[rg]);
    }
    __syncthreads();

    // Covariance partial: cov[i][j] += sum_px preT[i][px]*preT[j][px]
    // Symmetric: skip wave 2's tile (1,0) (transpose of wave 1's (0,1)).
    const int it = w >> 1, jt = w & 1;
    if (w != 2) {
        const bf16x8 ca = *(const bf16x8*)&preT[(it * 16 + lm) * 40 + quad * 8];
        const bf16x8 cb = *(const bf16x8*)&preT[(jt * 16 + lm) * 40 + quad * 8];
        f32x4 cacc = {0.f, 0.f, 0.f, 0.f};
        cacc = __builtin_amdgcn_mfma_f32_16x16x32_bf16(ca, cb, cacc, 0, 0, 0);
        float* pslot = &partials[(blockIdx.x & 63) * 1056];
#pragma unroll
        for (int rg = 0; rg < 4; ++rg) {
            const int ii = it * 16 + quad * 4 + rg, jj = jt * 16 + lm;
            atomicAdd(&pslot[ii * 32 + jj], cacc[rg]);
        }
    }
    // Per-channel sums: 128 threads, 4 segments of 8 px, vector read + shfl.
    if (tid < 128) {
        float* pslot = &partials[(blockIdx.x & 63) * 1056];
        const int cc = tid >> 2, sg = tid & 3;
        const uint4 pv = *(const uint4*)&preT[cc * 40 + sg * 8];
        const u16* pp = (const u16*)&pv;
        float s = 0.f;
#pragma unroll
        for (int p = 0; p < 8; ++p) s += us2f(pp[p]);
        s += __shfl_xor(s, 1);
        s += __shfl_xor(s, 2);
        if (sg == 0) atomicAdd(&pslot[1024 + cc], s);
    }
}

// ---------------------------------------------------------------------------
// K3 (MFMA, fused stats): out = x + A*(wf.pre) + S'. (R6-proven, unchanged.)
// ---------------------------------------------------------------------------
__global__ __launch_bounds__(256) void k_out(
    const bf16* __restrict__ pre, const float* __restrict__ wf,
    const float* __restrict__ partials, const float* __restrict__ gamma,
    const float* __restrict__ beta, const float* __restrict__ x,
    float* __restrict__ out)
{
    __shared__ u16 wh[256 * 40];   // 20480 B [out][ch] bf16-hi
    __shared__ u16 wl[256 * 40];   // 20480 B bf16-lo
    __shared__ u16 pL[32 * 40];    //  2560 B [px][ch]
    __shared__ float cov[1024];    //  4096 B
    __shared__ float mu[32];
    __shared__ float As[256];
    __shared__ float Ss[256];
    const int tid = threadIdx.x;
    const int gp0 = blockIdx.x * 32;
    const int b = gp0 >> 12, p0 = gp0 & 4095;

    // stage wf (f32) -> hi/lo bf16 LDS, 2048 float4 over 256 threads
#pragma unroll
    for (int i = 0; i < 8; ++i) {
        const int idx = tid + i * 256;       // 0..2047
        const int o = idx >> 3, c4 = idx & 7;
        const float4 v = *(const float4*)&wf[o * 32 + c4 * 4];
        ushort4 hv, lv;
        hv.x = f2u(v.x); lv.x = f2u(v.x - us2f(hv.x));
        hv.y = f2u(v.y); lv.y = f2u(v.y - us2f(hv.y));
        hv.z = f2u(v.z); lv.z = f2u(v.z - us2f(hv.z));
        hv.w = f2u(v.w); lv.w = f2u(v.w - us2f(hv.w));
        *(ushort4*)&wh[o * 40 + c4 * 4] = hv;
        *(ushort4*)&wl[o * 40 + c4 * 4] = lv;
    }
    if (tid < 128) {
        const int px = tid >> 2, c8 = tid & 3;
        *(uint4*)&pL[px * 40 + c8 * 8] =
            *(const uint4*)&((const u16*)pre)[(gp0 + px) * 32 + c8 * 8];
    }
    // reduce covariance partials (64 slots x 1056), L2/L3-resident
    {
        float4 a4 = {0.f, 0.f, 0.f, 0.f};
        for (int blk = 0; blk < 64; ++blk) {
            const float4 p = *(const float4*)&partials[blk * 1056 + tid * 4];
            a4.x += p.x; a4.y += p.y; a4.z += p.z; a4.w += p.w;
        }
        *(float4*)&cov[tid * 4] = a4;
    }
    if (tid < 32) {
        float s = 0.f;
        for (int blk = 0; blk < 64; ++blk) s += partials[blk * 1056 + 1024 + tid];
        mu[tid] = s * (1.f / 16384.f);
    }
    __syncthreads();

    // symmetry fixup: cov[i>=16][j<16] = cov[j][i] (disjoint read/write sets)
    {
        const int fi = 16 + (tid >> 4), fj = tid & 15;
        cov[fi * 32 + fj] = cov[fj * 32 + fi];
    }
    __syncthreads();

    // per-thread BN constants for channel o = tid
    {
        float wo[32];
#pragma unroll
        for (int c8 = 0; c8 < 4; ++c8) {
            const uint4 hv = *(const uint4*)&wh[tid * 40 + c8 * 8];
            const uint4 lv = *(const uint4*)&wl[tid * 40 + c8 * 8];
            const u16* hp = (const u16*)&hv;
            const u16* lp = (const u16*)&lv;
#pragma unroll
            for (int t = 0; t < 8; ++t)
                wo[c8 * 8 + t] = us2f(hp[t]) + us2f(lp[t]);
        }
        float mv = 0.f;
#pragma unroll
        for (int c = 0; c < 32; ++c) mv += wo[c] * mu[c];
        float qacc = 0.f;
        for (int i2 = 0; i2 < 32; ++i2) {
            float t = 0.f;
#pragma unroll
            for (int j2 = 0; j2 < 32; ++j2) t += wo[j2] * cov[i2 * 32 + j2];
            qacc += wo[i2] * t;
        }
        const float var = qacc * (1.f / 16384.f) - mv * mv;
        const float A = gamma[tid] * rsqrtf(var + 1e-5f);
        As[tid] = A;
        Ss[tid] = beta[tid] - A * mv;
    }
    __syncthreads();

    const int w = tid >> 6;
    const int lane = tid & 63;
    const int lm = lane & 15, quad = lane >> 4;

    bf16x8 pb[2];
    pb[0] = *(const bf16x8*)&pL[(0 + lm) * 40 + quad * 8];
    pb[1] = *(const bf16x8*)&pL[(16 + lm) * 40 + quad * 8];

    f32x4 acc[4][2];
#pragma unroll
    for (int mm = 0; mm < 4; ++mm) {
        const int orow = w * 64 + mm * 16 + lm;
        const bf16x8 ah = *(const bf16x8*)&wh[orow * 40 + quad * 8];
        const bf16x8 al = *(const bf16x8*)&wl[orow * 40 + quad * 8];
#pragma unroll
        for (int n = 0; n < 2; ++n) {
            f32x4 t = {0.f, 0.f, 0.f, 0.f};
            t = __builtin_amdgcn_mfma_f32_16x16x32_bf16(ah, pb[n], t, 0, 0, 0);
            acc[mm][n] =
                __builtin_amdgcn_mfma_f32_16x16x32_bf16(al, pb[n], t, 0, 0, 0);
        }
    }

#pragma unroll
    for (int mm = 0; mm < 4; ++mm) {
#pragma unroll
        for (int rg = 0; rg < 4; ++rg) {
            const int o = w * 64 + mm * 16 + quad * 4 + rg;
            const float Ao = As[o], So = Ss[o];
#pragma unroll
            for (int n = 0; n < 2; ++n) {
                const int ga = ((b << 8) + o) * 4096 + p0 + n * 16 + lm;
                out[ga] = x[ga] + Ao * acc[mm][n][rg] + So;
            }
        }
    }
}

extern "C" void kernel_launch(void* const* d_in, const int* in_sizes, int n_in,
                              void* d_out, int out_size, void* d_ws, size_t ws_size,
                              hipStream_t stream)
{
    (void)in_sizes; (void)n_in; (void)out_size; (void)ws_size;
    float* out = (float*)d_out;
    char* ws = (char*)d_ws;

    const float* x      = (const float*)d_in[0];
    const float* vessel = (const float*)d_in[1];
    const float* wk     = (const float*)d_in[2];
    const float* bk     = (const float*)d_in[3];
    const float* wq     = (const float*)d_in[4];
    const float* bq     = (const float*)d_in[5];
    const float* wx     = (const float*)d_in[6];
    const float* bx     = (const float*)d_in[7];
    const float* wf     = (const float*)d_in[8];
    // d_in[9] (bfb) cancels algebraically in training-mode BN — unused.
    const float* gamma  = (const float*)d_in[10];
    const float* beta   = (const float*)d_in[11];

    // Disjoint workspace layout:
    bf16* km  = (bf16*)(ws);
    bf16* qm  = (bf16*)(ws + 1048576);
    bf16* xm  = (bf16*)(ws + 2097152);
    bf16* pre = (bf16*)(ws + 3145728);
    float* partials = (float*)(ws + 4194304);   // 64*1056*4 = 270336 B

    k_proj <<<512, 256, 0, stream>>>(x, vessel, wk, bk, wq, bq, wx, bx,
                                     km, qm, xm, partials);
    k_attn <<<512, 256, 0, stream>>>(km, qm, xm, pre, partials);
    k_out  <<<512, 256, 0, stream>>>(pre, wf, partials, gamma, beta, x, out);
}

// Round 8
// 123.120 us; speedup vs baseline: 1.0129x; 1.0129x over previous
//
#include <hip/hip_runtime.h>
#include <hip/hip_bf16.h>

typedef __hip_bfloat16 bf16;
typedef unsigned short u16;
typedef unsigned int u32;

typedef __bf16 bf16x8 __attribute__((ext_vector_type(8)));
typedef float f32x4 __attribute__((ext_vector_type(4)));

__device__ __forceinline__ float bf2f(bf16 v) { return __bfloat162float(v); }
__device__ __forceinline__ float us2f(u16 u) {
    union { u32 i; float f; } c; c.i = ((u32)u) << 16; return c.f;
}
__device__ __forceinline__ u16 f2u(float f) {
    union { bf16 b; u16 u; } c; c.b = __float2bfloat16(f); return c.u;
}

// ---------------------------------------------------------------------------
// K1 (MFMA GEMM): km/qm/xm = conv1x1. Blocks 0..63 zero the covariance
// partials arena. (R6-proven, unchanged.)
// ---------------------------------------------------------------------------
__global__ __launch_bounds__(256) void k_proj(
    const float* __restrict__ x, const float* __restrict__ vessel,
    const float* __restrict__ wk, const float* __restrict__ bk,
    const float* __restrict__ wq, const float* __restrict__ bq,
    const float* __restrict__ wx, const float* __restrict__ bx,
    bf16* __restrict__ km, bf16* __restrict__ qm, bf16* __restrict__ xm,
    float* __restrict__ partials)
{
    __shared__ u16 xs[64 * 264];
    __shared__ u16 wsh[48 * 264];
    const int tid = threadIdx.x;
    const int bid = blockIdx.x;
    const int nh = bid & 1;
    const int pt = bid >> 1;
    const int b  = pt >> 6;
    const int p0 = (pt & 63) * 64;

    if (bid < 64) {
#pragma unroll
        for (int i = 0; i < 5; ++i) {
            const int idx = tid + i * 256;
            if (idx < 1056) partials[bid * 1056 + idx] = 0.f;
        }
    }

#pragma unroll
    for (int i = 0; i < 16; ++i) {
        const int idx4 = tid + i * 256;
        const int ch = idx4 >> 4;
        const int px4 = (idx4 & 15) * 4;
        const float4 v = *(const float4*)&x[(b * 256 + ch) * 4096 + p0 + px4];
        xs[(px4 + 0) * 264 + ch] = f2u(v.x);
        xs[(px4 + 1) * 264 + ch] = f2u(v.y);
        xs[(px4 + 2) * 264 + ch] = f2u(v.z);
        xs[(px4 + 3) * 264 + ch] = f2u(v.w);
    }
#pragma unroll
    for (int i = 0; i < 12; ++i) {
        const int idx4 = tid + i * 256;
        const int o = idx4 >> 6;
        const int ch4 = (idx4 & 63) * 4;
        const int go = nh * 48 + o;
        const float* wp = (go < 32) ? wk : ((go < 64) ? wq : wx);
        const float4 v = *(const float4*)&wp[(go & 31) * 256 + ch4];
        wsh[o * 264 + ch4 + 0] = f2u(v.x);
        wsh[o * 264 + ch4 + 1] = f2u(v.y);
        wsh[o * 264 + ch4 + 2] = f2u(v.z);
        wsh[o * 264 + ch4 + 3] = f2u(v.w);
    }
    __syncthreads();

    const int w = tid >> 6;
    const int lane = tid & 63;
    const int lm = lane & 15, quad = lane >> 4;

    f32x4 acc0 = {0.f, 0.f, 0.f, 0.f};
    f32x4 acc1 = {0.f, 0.f, 0.f, 0.f};
    f32x4 acc2 = {0.f, 0.f, 0.f, 0.f};
#pragma unroll
    for (int kk = 0; kk < 8; ++kk) {
        const int k0 = kk * 32 + quad * 8;
        const bf16x8 a  = *(const bf16x8*)&xs[(w * 16 + lm) * 264 + k0];
        const bf16x8 b0 = *(const bf16x8*)&wsh[(0 + lm) * 264 + k0];
        const bf16x8 b1 = *(const bf16x8*)&wsh[(16 + lm) * 264 + k0];
        const bf16x8 b2 = *(const bf16x8*)&wsh[(32 + lm) * 264 + k0];
        acc0 = __builtin_amdgcn_mfma_f32_16x16x32_bf16(a, b0, acc0, 0, 0, 0);
        acc1 = __builtin_amdgcn_mfma_f32_16x16x32_bf16(a, b1, acc1, 0, 0, 0);
        acc2 = __builtin_amdgcn_mfma_f32_16x16x32_bf16(a, b2, acc2, 0, 0, 0);
    }
#pragma unroll
    for (int t = 0; t < 3; ++t) {
        const f32x4 acc = (t == 0) ? acc0 : ((t == 1) ? acc1 : acc2);
        const int go = nh * 48 + t * 16 + lm;
        const float* bs = (go < 32) ? bk : ((go < 64) ? bq : bx);
        const float bias = bs[go & 31];
        bf16* dst = (go < 32) ? km : ((go < 64) ? qm : xm);
#pragma unroll
        for (int rg = 0; rg < 4; ++rg) {
            const int px = p0 + w * 16 + quad * 4 + rg;
            float vv = acc[rg] + bias;
            if (go < 32) vv *= vessel[b * 4096 + px];
            dst[(b * 4096 + px) * 32 + (go & 31)] = __float2bfloat16(vv);
        }
    }
}

// ---------------------------------------------------------------------------
// K2 (MFMA): 4-scale local attention. R6-proven structure (best measured);
// single R7-retained change: Q fragments loaded ONCE per lane (2 loads, was
// 6 redundant) and issued before the barrier to overlap staging.
// Block = 4x8 px tile, grid 512, LDS 53248 B, 3 blocks/CU.
// Cov partial: symmetric -> wave 2's tile (1,0) skipped, rebuilt in k_out.
// ---------------------------------------------------------------------------
__global__ __launch_bounds__(256, 3) void k_attn(
    const bf16* __restrict__ km, const bf16* __restrict__ qm,
    const bf16* __restrict__ xm, bf16* __restrict__ pre,
    float* __restrict__ partials)
{
    __shared__ u16 kT[192 * 40];     // 15360 B; reused as P[32*200] after S
    __shared__ u16 xTt[32 * 200];    // 12800 B  [ch][pos]
    __shared__ float S[32 * 196];    // 25088 B  [px][pos]; reused as preT
    u16* P = kT;                     // P[px*200+pos] (kT dead after Phase A)
    u16* preT = (u16*)S;             // preT[ch*40+px] (S dead after Phase B)

    const int tid = threadIdx.x;
    const int b = blockIdx.x >> 7;
    const int t128 = blockIdx.x & 127;
    const int h0 = (t128 >> 3) * 4;          // 16 row-tiles of 4
    const int w0 = (t128 & 7) * 8;           // 8 col-tiles of 8
    const u16* uk = (const u16*)km;
    const u16* ux = (const u16*)xm;
    const u16* uq = (const u16*)qm;
    const uint4 z4 = {0u, 0u, 0u, 0u};

    const int w = tid >> 6;
    const int lane = tid & 63;
    const int lm = lane & 15, quad = lane >> 4;

    // stage kT [pos][ch] + xTt [ch][pos] (transposed): 192 pos x 4 c8
#pragma unroll
    for (int i = 0; i < 3; ++i) {
        const int idx4 = tid + i * 256;      // 0..767
        const int pos = idx4 >> 2, c8 = idx4 & 3;
        const int gh = h0 - 4 + (pos >> 4), gw = w0 - 4 + (pos & 15);
        uint4 kv = z4, xv = z4;
        if (gh >= 0 && gh < 64 && gw >= 0 && gw < 64) {
            const int g = ((b << 12) + (gh << 6) + gw) * 32 + c8 * 8;
            kv = *(const uint4*)&uk[g];
            xv = *(const uint4*)&ux[g];
        }
        *(uint4*)&kT[pos * 40 + c8 * 8] = kv;
        const u16* xu = (const u16*)&xv;
#pragma unroll
        for (int t = 0; t < 8; ++t)
            xTt[(c8 * 8 + t) * 200 + pos] = xu[t];
    }
    // Q fragments: 2 distinct per lane (m = 0,1); issued pre-barrier
    bf16x8 qa[2];
#pragma unroll
    for (int m = 0; m < 2; ++m) {
        const int am = m * 16 + lm;
        const int qgh = h0 + (am >> 3), qgw = w0 + (am & 7);
        qa[m] = *(const bf16x8*)&uq[(((b << 12) + (qgh << 6) + qgw) << 5) + quad * 8];
    }
    __syncthreads();

    // Phase A: S tiles. 24 tiles (m 0..1, n 0..11), wave w takes t=w+4i.
#pragma unroll
    for (int i = 0; i < 6; ++i) {
        const int t = w + i * 4;
        const int m = t / 12, n = t - m * 12;
        const bf16x8 bb = *(const bf16x8*)&kT[(n * 16 + lm) * 40 + quad * 8];
        f32x4 acc = {0.f, 0.f, 0.f, 0.f};
        acc = __builtin_amdgcn_mfma_f32_16x16x32_bf16(qa[m], bb, acc, 0, 0, 0);
#pragma unroll
        for (int rg = 0; rg < 4; ++rg)
            S[(m * 16 + quad * 4 + rg) * 196 + n * 16 + lm] = acc[rg];
    }
    __syncthreads();

    // Phase B: per-thread 24 positions of one pixel (stride-8, conflict-free)
    const int px = tid >> 3, cg = tid & 7;
    const int ty = px >> 3, tx = px & 7;
    float e[24];
    float Z3 = 0.f, Z5 = 0.f, Z7 = 0.f, Z9 = 0.f;
#pragma unroll
    for (int i = 0; i < 24; ++i) {
        const int pos = cg + 8 * i;
        const int hy = pos >> 4, hx = pos & 15;
        const int dy = hy - 4 - ty, dx = hx - 4 - tx;
        const int ady = dy < 0 ? -dy : dy, adx = dx < 0 ? -dx : dx;
        const int r = ady > adx ? ady : adx;
        const float s = S[px * 196 + pos];
        const float ev = (r <= 4) ? __expf(s) : 0.f;
        e[i] = ev;
        if (r <= 1) Z3 += ev;
        if (r <= 2) Z5 += ev;
        if (r <= 3) Z7 += ev;
        Z9 += ev;
    }
#pragma unroll
    for (int m = 1; m <= 4; m <<= 1) {
        Z3 += __shfl_xor(Z3, m);
        Z5 += __shfl_xor(Z5, m);
        Z7 += __shfl_xor(Z7, m);
        Z9 += __shfl_xor(Z9, m);
    }
    const float iZ3 = 1.f / Z3, iZ5 = 1.f / Z5, iZ7 = 1.f / Z7, iZ9 = 1.f / Z9;
#pragma unroll
    for (int i = 0; i < 24; ++i) {
        const int pos = cg + 8 * i;
        const int hy = pos >> 4, hx = pos & 15;
        const int dy = hy - 4 - ty, dx = hx - 4 - tx;
        const int ady = dy < 0 ? -dy : dy, adx = dx < 0 ? -dx : dx;
        const int r = ady > adx ? ady : adx;
        float coef = iZ9;
        if (r <= 1) coef += iZ3;
        if (r <= 2) coef += iZ5;
        if (r <= 3) coef += iZ7;
        P[px * 200 + pos] = f2u(e[i] * coef);
    }
    __syncthreads();

    // Phase C: pre(32x32) = P(32x192) . X^T : wave w -> tile (m0,n0)
    const int m0 = w >> 1, n0 = w & 1;
    f32x4 acc = {0.f, 0.f, 0.f, 0.f};
#pragma unroll
    for (int kk = 0; kk < 6; ++kk) {
        const int k0 = kk * 32 + quad * 8;
        const bf16x8 a = *(const bf16x8*)&P[(m0 * 16 + lm) * 200 + k0];
        const bf16x8 bb = *(const bf16x8*)&xTt[(n0 * 16 + lm) * 200 + k0];
        acc = __builtin_amdgcn_mfma_f32_16x16x32_bf16(a, bb, acc, 0, 0, 0);
    }
#pragma unroll
    for (int rg = 0; rg < 4; ++rg) {
        const int pl = m0 * 16 + quad * 4 + rg;
        const int gh = h0 + (pl >> 3), gw = w0 + (pl & 7);
        pre[(((b << 12) + (gh << 6) + gw) << 5) + n0 * 16 + lm] =
            __float2bfloat16(acc[rg]);
        // transposed bf16 copy for the covariance MFMA: preT[ch][px]
        preT[(n0 * 16 + lm) * 40 + pl] = f2u(acc[rg]);
    }
    __syncthreads();

    // Covariance partial: cov[i][j] += sum_px preT[i][px]*preT[j][px]
    // Symmetric: skip wave 2's tile (1,0) (transpose of wave 1's (0,1)).
    const int it = w >> 1, jt = w & 1;
    if (w != 2) {
        const bf16x8 ca = *(const bf16x8*)&preT[(it * 16 + lm) * 40 + quad * 8];
        const bf16x8 cb = *(const bf16x8*)&preT[(jt * 16 + lm) * 40 + quad * 8];
        f32x4 cacc = {0.f, 0.f, 0.f, 0.f};
        cacc = __builtin_amdgcn_mfma_f32_16x16x32_bf16(ca, cb, cacc, 0, 0, 0);
        float* pslot = &partials[(blockIdx.x & 63) * 1056];
#pragma unroll
        for (int rg = 0; rg < 4; ++rg) {
            const int ii = it * 16 + quad * 4 + rg, jj = jt * 16 + lm;
            atomicAdd(&pslot[ii * 32 + jj], cacc[rg]);
        }
    }
    // Per-channel sums: 128 threads, 4 segments of 8 px each, shfl-reduce.
    if (tid < 128) {
        float* pslot = &partials[(blockIdx.x & 63) * 1056];
        const int cc = tid >> 2, sg = tid & 3;
        float s = 0.f;
#pragma unroll
        for (int p = 0; p < 8; ++p) s += us2f(preT[cc * 40 + sg * 8 + p]);
        s += __shfl_xor(s, 1);
        s += __shfl_xor(s, 2);
        if (sg == 0) atomicAdd(&pslot[1024 + cc], s);
    }
}

// ---------------------------------------------------------------------------
// K3 (MFMA, fused stats): out = x + A*(wf.pre) + S'. (R6-proven, unchanged.)
// ---------------------------------------------------------------------------
__global__ __launch_bounds__(256) void k_out(
    const bf16* __restrict__ pre, const float* __restrict__ wf,
    const float* __restrict__ partials, const float* __restrict__ gamma,
    const float* __restrict__ beta, const float* __restrict__ x,
    float* __restrict__ out)
{
    __shared__ u16 wh[256 * 40];   // 20480 B [out][ch] bf16-hi
    __shared__ u16 wl[256 * 40];   // 20480 B bf16-lo
    __shared__ u16 pL[32 * 40];    //  2560 B [px][ch]
    __shared__ float cov[1024];    //  4096 B
    __shared__ float mu[32];
    __shared__ float As[256];
    __shared__ float Ss[256];
    const int tid = threadIdx.x;
    const int gp0 = blockIdx.x * 32;
    const int b = gp0 >> 12, p0 = gp0 & 4095;

    // stage wf (f32) -> hi/lo bf16 LDS, 2048 float4 over 256 threads
#pragma unroll
    for (int i = 0; i < 8; ++i) {
        const int idx = tid + i * 256;       // 0..2047
        const int o = idx >> 3, c4 = idx & 7;
        const float4 v = *(const float4*)&wf[o * 32 + c4 * 4];
        ushort4 hv, lv;
        hv.x = f2u(v.x); lv.x = f2u(v.x - us2f(hv.x));
        hv.y = f2u(v.y); lv.y = f2u(v.y - us2f(hv.y));
        hv.z = f2u(v.z); lv.z = f2u(v.z - us2f(hv.z));
        hv.w = f2u(v.w); lv.w = f2u(v.w - us2f(hv.w));
        *(ushort4*)&wh[o * 40 + c4 * 4] = hv;
        *(ushort4*)&wl[o * 40 + c4 * 4] = lv;
    }
    if (tid < 128) {
        const int px = tid >> 2, c8 = tid & 3;
        *(uint4*)&pL[px * 40 + c8 * 8] =
            *(const uint4*)&((const u16*)pre)[(gp0 + px) * 32 + c8 * 8];
    }
    // reduce covariance partials (64 slots x 1056), L2/L3-resident
    {
        float4 a4 = {0.f, 0.f, 0.f, 0.f};
        for (int blk = 0; blk < 64; ++blk) {
            const float4 p = *(const float4*)&partials[blk * 1056 + tid * 4];
            a4.x += p.x; a4.y += p.y; a4.z += p.z; a4.w += p.w;
        }
        *(float4*)&cov[tid * 4] = a4;
    }
    if (tid < 32) {
        float s = 0.f;
        for (int blk = 0; blk < 64; ++blk) s += partials[blk * 1056 + 1024 + tid];
        mu[tid] = s * (1.f / 16384.f);
    }
    __syncthreads();

    // symmetry fixup: cov[i>=16][j<16] = cov[j][i] (disjoint read/write sets)
    {
        const int fi = 16 + (tid >> 4), fj = tid & 15;
        cov[fi * 32 + fj] = cov[fj * 32 + fi];
    }
    __syncthreads();

    // per-thread BN constants for channel o = tid
    {
        float wo[32];
#pragma unroll
        for (int c8 = 0; c8 < 4; ++c8) {
            const uint4 hv = *(const uint4*)&wh[tid * 40 + c8 * 8];
            const uint4 lv = *(const uint4*)&wl[tid * 40 + c8 * 8];
            const u16* hp = (const u16*)&hv;
            const u16* lp = (const u16*)&lv;
#pragma unroll
            for (int t = 0; t < 8; ++t)
                wo[c8 * 8 + t] = us2f(hp[t]) + us2f(lp[t]);
        }
        float mv = 0.f;
#pragma unroll
        for (int c = 0; c < 32; ++c) mv += wo[c] * mu[c];
        float qacc = 0.f;
        for (int i2 = 0; i2 < 32; ++i2) {
            float t = 0.f;
#pragma unroll
            for (int j2 = 0; j2 < 32; ++j2) t += wo[j2] * cov[i2 * 32 + j2];
            qacc += wo[i2] * t;
        }
        const float var = qacc * (1.f / 16384.f) - mv * mv;
        const float A = gamma[tid] * rsqrtf(var + 1e-5f);
        As[tid] = A;
        Ss[tid] = beta[tid] - A * mv;
    }
    __syncthreads();

    const int w = tid >> 6;
    const int lane = tid & 63;
    const int lm = lane & 15, quad = lane >> 4;

    bf16x8 pb[2];
    pb[0] = *(const bf16x8*)&pL[(0 + lm) * 40 + quad * 8];
    pb[1] = *(const bf16x8*)&pL[(16 + lm) * 40 + quad * 8];

    f32x4 acc[4][2];
#pragma unroll
    for (int mm = 0; mm < 4; ++mm) {
        const int orow = w * 64 + mm * 16 + lm;
        const bf16x8 ah = *(const bf16x8*)&wh[orow * 40 + quad * 8];
        const bf16x8 al = *(const bf16x8*)&wl[orow * 40 + quad * 8];
#pragma unroll
        for (int n = 0; n < 2; ++n) {
            f32x4 t = {0.f, 0.f, 0.f, 0.f};
            t = __builtin_amdgcn_mfma_f32_16x16x32_bf16(ah, pb[n], t, 0, 0, 0);
            acc[mm][n] =
                __builtin_amdgcn_mfma_f32_16x16x32_bf16(al, pb[n], t, 0, 0, 0);
        }
    }

#pragma unroll
    for (int mm = 0; mm < 4; ++mm) {
#pragma unroll
        for (int rg = 0; rg < 4; ++rg) {
            const int o = w * 64 + mm * 16 + quad * 4 + rg;
            const float Ao = As[o], So = Ss[o];
#pragma unroll
            for (int n = 0; n < 2; ++n) {
                const int ga = ((b << 8) + o) * 4096 + p0 + n * 16 + lm;
                out[ga] = x[ga] + Ao * acc[mm][n][rg] + So;
            }
        }
    }
}

extern "C" void kernel_launch(void* const* d_in, const int* in_sizes, int n_in,
                              void* d_out, int out_size, void* d_ws, size_t ws_size,
                              hipStream_t stream)
{
    (void)in_sizes; (void)n_in; (void)out_size; (void)ws_size;
    float* out = (float*)d_out;
    char* ws = (char*)d_ws;

    const float* x      = (const float*)d_in[0];
    const float* vessel = (const float*)d_in[1];
    const float* wk     = (const float*)d_in[2];
    const float* bk     = (const float*)d_in[3];
    const float* wq     = (const float*)d_in[4];
    const float* bq     = (const float*)d_in[5];
    const float* wx     = (const float*)d_in[6];
    const float* bx     = (const float*)d_in[7];
    const float* wf     = (const float*)d_in[8];
    // d_in[9] (bfb) cancels algebraically in training-mode BN — unused.
    const float* gamma  = (const float*)d_in[10];
    const float* beta   = (const float*)d_in[11];

    // Disjoint workspace layout:
    bf16* km  = (bf16*)(ws);
    bf16* qm  = (bf16*)(ws + 1048576);
    bf16* xm  = (bf16*)(ws + 2097152);
    bf16* pre = (bf16*)(ws + 3145728);
    float* partials = (float*)(ws + 4194304);   // 64*1056*4 = 270336 B

    k_proj <<<512, 256, 0, stream>>>(x, vessel, wk, bk, wq, bq, wx, bx,
                                     km, qm, xm, partials);
    k_attn <<<512, 256, 0, stream>>>(km, qm, xm, pre, partials);
    k_out  <<<512, 256, 0, stream>>>(pre, wf, partials, gamma, beta, x, out);
}